// Round 6
// baseline (1830.167 us; speedup 1.0000x reference)
//
#include <hip/hip_runtime.h>
#include <math.h>

// LSTM autoencoder, MFMA, R6 = R5 (BN folded into weights at pack time)
// + restored error-compensated numerics:
//  - states split RNE-hi + trunc-lo (R3/R4 scheme)
//  - every matmul uses 3 products: Ah*Bh + Al*Bh + Ah*Bl  (B lo restored;
//    R2 showed this makes MFMA quantization invisible vs harness floor)
// 128 blocks x 512 threads, BT=16 rows/block.

typedef __attribute__((ext_vector_type(8))) short short8;
typedef __attribute__((ext_vector_type(4))) float floatx4;

#define TT 128
#define NF 8
#define BT 16
#define NBLK 128
#define NTH 512

// packed-fragment start indices (in 1024-ushort frag units); hi at +0, lo at +512
#define FS_Z1 0     // K'=160 (Wr1 128 | Wk1 8 | pad), N=512 : 32 tiles x 5 ks
#define FS_Z2 160   // K'=192 (s1*Wk2 128 | Wr2 64),  N=256 : 16 x 6
#define FS_X3 256   // K =64  (s2*Wk3),               N=256 : 16 x 2
#define FS_Z3 288   // K =64  (Wr3),                  N=256 : 16 x 2
#define FS_Z4 320   // K'=192 (s3*Wk4 64 | Wr4 128),  N=512 : 32 x 6
#define FS_DN 512   // K =128 (s4*Wd), N=16 (cols 8-15 zero) : 1 x 4
#define N_FRAGS 516
// float bias area after frags (ushort offset N_FRAGS*1024):
//   [0,256) bias2' | [256,512) bias3' | [512,1024) bias4' | [1024,1032) biasd'

#define MFMA(a,b,c) __builtin_amdgcn_mfma_f32_16x16x32_bf16((a),(b),(c),0,0,0)

__device__ __forceinline__ unsigned short bf16hi(float x){ // RNE
    unsigned u = __float_as_uint(x);
    u += 0x7fffu + ((u >> 16) & 1u);
    return (unsigned short)(u >> 16);
}
__device__ __forceinline__ unsigned short bf16tr(float x){ // truncate
    return (unsigned short)(__float_as_uint(x) >> 16);
}
__device__ __forceinline__ float bf16f(unsigned short h){
    return __uint_as_float(((unsigned)h) << 16);
}
__device__ __forceinline__ void hilo(float x, unsigned short& hi, unsigned short& lo){
    hi = bf16hi(x);                        // RNE hi
    lo = bf16tr(x - bf16f(hi));            // truncated residual
}
__device__ __forceinline__ float sigmoid_(float x){ return 1.0f/(1.0f+__expf(-x)); }
__device__ __forceinline__ float selu_(float x){
    const float alpha = 1.6732632423543772f, scale = 1.0507009873554805f;
    return x > 0.0f ? scale*x : scale*alpha*(__expf(x)-1.0f);
}

// ---------------- pack kernel -----------------------------------------------
__global__ void pack_kernel(const float* __restrict__ Wk1, const float* __restrict__ Wr1,
                            const float* __restrict__ Wk2, const float* __restrict__ Wr2,
                            const float* __restrict__ Wk3, const float* __restrict__ Wr3,
                            const float* __restrict__ Wk4, const float* __restrict__ Wr4,
                            const float* __restrict__ Wd,
                            const float* __restrict__ g1, const float* __restrict__ be1, const float* __restrict__ m1, const float* __restrict__ v1,
                            const float* __restrict__ g2, const float* __restrict__ be2, const float* __restrict__ m2, const float* __restrict__ v2,
                            const float* __restrict__ g3, const float* __restrict__ be3, const float* __restrict__ m3, const float* __restrict__ v3,
                            const float* __restrict__ g4, const float* __restrict__ be4, const float* __restrict__ m4, const float* __restrict__ v4,
                            const float* __restrict__ b2, const float* __restrict__ b3,
                            const float* __restrict__ b4, const float* __restrict__ bd,
                            unsigned short* __restrict__ ws)
{
    const int g = blockIdx.x;
    const int l = threadIdx.x;

    if (g >= N_FRAGS){                       // folded-bias blocks: b' = b + t@W
        const int bb = g - N_FRAGS;
        float* fb = (float*)(ws + (size_t)N_FRAGS*1024);
        if (bb == 0){
            for (int c = l; c < 256; c += 64){
                float acc = b2[c];
                for (int u = 0; u < 128; ++u){
                    float s = g1[u]*rsqrtf(v1[u]+1e-3f);
                    acc += (be1[u]-m1[u]*s) * Wk2[u*256 + c];
                }
                fb[c] = acc;
            }
        } else if (bb == 1){
            for (int c = l; c < 256; c += 64){
                float acc = b3[c];
                for (int u = 0; u < 64; ++u){
                    float s = g2[u]*rsqrtf(v2[u]+1e-3f);
                    acc += (be2[u]-m2[u]*s) * Wk3[u*256 + c];
                }
                fb[256 + c] = acc;
            }
        } else if (bb == 2){
            for (int c = l; c < 512; c += 64){
                float acc = b4[c];
                for (int u = 0; u < 64; ++u){
                    float s = g3[u]*rsqrtf(v3[u]+1e-3f);
                    acc += (be3[u]-m3[u]*s) * Wk4[u*512 + c];
                }
                fb[512 + c] = acc;
            }
        } else {
            if (l < 8){
                float acc = bd[l];
                for (int u = 0; u < 128; ++u){
                    float s = g4[u]*rsqrtf(v4[u]+1e-3f);
                    acc += (be4[u]-m4[u]*s) * Wd[u*8 + l];
                }
                fb[1024 + l] = acc;
            }
        }
        return;
    }

    int blob, fs, KS;
    if      (g < FS_Z2){ blob = 0; fs = FS_Z1; KS = 5; }
    else if (g < FS_X3){ blob = 1; fs = FS_Z2; KS = 6; }
    else if (g < FS_Z3){ blob = 2; fs = FS_X3; KS = 2; }
    else if (g < FS_Z4){ blob = 3; fs = FS_Z3; KS = 2; }
    else if (g < FS_DN){ blob = 4; fs = FS_Z4; KS = 6; }
    else               { blob = 5; fs = FS_DN; KS = 4; }
    const int fl = g - fs;
    const int tile = fl / KS, kk = fl % KS;
    const int col = tile * 16 + (l & 15);
    const int k0  = kk * 32 + (l >> 4) * 8;

    short8 hi8, lo8;
    #pragma unroll
    for (int j = 0; j < 8; ++j){
        const int k = k0 + j;
        float v = 0.0f;
        switch (blob){
            case 0: v = (k < 128) ? Wr1[k*512 + col] : (k < 136 ? Wk1[(k-128)*512 + col] : 0.0f); break;
            case 1: // s1-scaled Wk2 | raw Wr2
                if (k < 128) v = Wk2[k*256 + col] * (g1[k]*rsqrtf(v1[k]+1e-3f));
                else         v = Wr2[(k-128)*256 + col];
                break;
            case 2: v = Wk3[k*256 + col] * (g2[k]*rsqrtf(v2[k]+1e-3f)); break;
            case 3: v = Wr3[k*256 + col]; break;
            case 4: // s3-scaled Wk4 | raw Wr4
                if (k < 64) v = Wk4[k*512 + col] * (g3[k]*rsqrtf(v3[k]+1e-3f));
                else        v = Wr4[(k-64)*512 + col];
                break;
            case 5: v = (col < 8) ? Wd[k*8 + col] * (g4[k]*rsqrtf(v4[k]+1e-3f)) : 0.0f; break;
        }
        unsigned short h = bf16hi(v);
        unsigned short lo = bf16hi(v - bf16f(h));
        hi8[j] = (short)h; lo8[j] = (short)lo;
    }
    *(short8*)(ws + (size_t)g*1024 + l*8)       = hi8;
    *(short8*)(ws + (size_t)g*1024 + 512 + l*8) = lo8;
}

// ---------------- main kernel ------------------------------------------------
__global__ __launch_bounds__(NTH, 1) void lstm_ae_mfma(
    const float* __restrict__ x,
    const float* __restrict__ b1,
    const unsigned short* __restrict__ WS,
    float* __restrict__ out)
{
    // A-fragment planes: [hi/lo][kk][lane*8 + j]
    __shared__ __align__(16) short AZ1[2][2][5][512];   // h1 (kk 0-3) + x (kk 4)
    __shared__ __align__(16) short AH2[2][2][2][512];
    __shared__ __align__(16) short AH3[2][2][2][512];
    __shared__ __align__(16) short AH4[2][2][4][512];
    __shared__ __align__(16) float ZSC[16*260];

    const int tid = threadIdx.x;
    const int w = tid >> 6, l = tid & 63;
    const int l15 = l & 15, q = l >> 4;
    const int b0 = blockIdx.x * BT;
    const float* FB = (const float*)(WS + (size_t)N_FRAGS*1024);

    // ---- per-lane constants ----
    const int u1 = 16*w + l15;
    const int kk1 = u1 >> 5;
    const int sbase1 = ((u1>>3)&3)*128 + (u1&7);

    const int c2row = l15;
    int kk2[2], s2i[2], u2k[2];
    #pragma unroll
    for (int k2 = 0; k2 < 2; ++k2){
        const int u = (l>>4) + 4*w + 32*k2;
        u2k[k2] = u;
        kk2[k2] = u >> 5;
        s2i[k2] = (((u>>3)&3)*16 + c2row)*8 + (u&7);
    }

    float z1b[4], z4b[4], z2b[2], b3v[2];
    #pragma unroll
    for (int i = 0; i < 4; ++i){
        z1b[i] = b1[(w + 8*i)*16 + l15];
        z4b[i] = FB[512 + (w + 8*i)*16 + l15];
    }
    #pragma unroll
    for (int i = 0; i < 2; ++i){
        z2b[i] = FB[32*w + 16*i + l15];
        b3v[i] = FB[256 + 32*w + 16*i + l15];
    }
    const float bdv = (w == 0 && l15 < 8) ? FB[1024 + l15] : 0.0f;

    // per-wave fragment base pointers (lane offset folded in)
    const unsigned short* PZ1 = WS + (size_t)(FS_Z1 + w*5)*1024 + l*8;   // + (i*8*5 + kk)*1024
    const unsigned short* PZ2 = WS + (size_t)(FS_Z2 + 2*w*6)*1024 + l*8; // + (i*6 + kk)*1024
    const unsigned short* PX3 = WS + (size_t)(FS_X3 + 2*w*2)*1024 + l*8;
    const unsigned short* PZ3 = WS + (size_t)(FS_Z3 + 2*w*2)*1024 + l*8;
    const unsigned short* PZ4 = WS + (size_t)(FS_Z4 + w*6)*1024 + l*8;   // + (i*8*6 + kk)*1024
    const unsigned short* PDN = WS + (size_t)FS_DN*1024 + l*8;

    // ---- prologue: zero t=0 state planes, stage x[0] ----
    for (int i = tid; i < 5120; i += NTH) ((int*)AZ1)[i] = 0;
    for (int i = tid; i < 2048; i += NTH){ ((int*)AH2)[i] = 0; ((int*)AH3)[i] = 0; }
    for (int i = tid; i < 4096; i += NTH) ((int*)AH4)[i] = 0;
    if (tid < 128){
        int row = tid >> 3, j = tid & 7;
        unsigned short xh, xl;
        hilo(x[(size_t)(b0+row)*(TT*NF) + j], xh, xl);
        AZ1[0][0][4][row*8+j] = (short)xh;
        AZ1[0][1][4][row*8+j] = (short)xl;
    }
    float c1r[4] = {0,0,0,0}, c4r[4] = {0,0,0,0};
    float c2r[2] = {0,0}, c3r[2] = {0,0};
    __syncthreads();

    // ===================== encoder (2 barriers/step) =====================
    int p = 0;
    for (int t = 0; t < TT; ++t){
        float xnext = 0.0f;
        if (tid < 128 && t+1 < TT)
            xnext = x[(size_t)(b0+(tid>>3))*(TT*NF) + (size_t)(t+1)*NF + (tid&7)];

        // --- z1 ---
        floatx4 acc[4];
        #pragma unroll
        for (int i = 0; i < 4; ++i) acc[i] = (floatx4){z1b[i],z1b[i],z1b[i],z1b[i]};
        #pragma unroll
        for (int kk = 0; kk < 5; ++kk){
            short8 ah = *(const short8*)&AZ1[p][0][kk][l*8];
            short8 al = *(const short8*)&AZ1[p][1][kk][l*8];
            #pragma unroll
            for (int i = 0; i < 4; ++i){
                const unsigned short* bp = PZ1 + (size_t)(i*40 + kk)*1024;
                short8 bh = *(const short8*)bp;
                short8 bl = *(const short8*)(bp + 512);
                acc[i] = MFMA(ah, bh, acc[i]);
                acc[i] = MFMA(al, bh, acc[i]);
                acc[i] = MFMA(ah, bl, acc[i]);
            }
        }
        // --- cell1 (raw h; BN1 folded into Wk2) ---
        #pragma unroll
        for (int r = 0; r < 4; ++r){
            float ig = sigmoid_(acc[0][r]);
            float fg = sigmoid_(acc[1][r]);
            float gg = selu_(acc[2][r]);
            float og = sigmoid_(acc[3][r]);
            float c = fg*c1r[r] + ig*gg; c1r[r] = c;
            float h = og*selu_(c);
            unsigned short hh, hl; hilo(h, hh, hl);
            const int s = sbase1 + (q*4+r)*8;
            AZ1[p^1][0][kk1][s] = (short)hh;
            AZ1[p^1][1][kk1][s] = (short)hl;
        }
        if (tid < 128 && t+1 < TT){
            int row = tid >> 3, j = tid & 7;
            unsigned short xh, xl; hilo(xnext, xh, xl);
            AZ1[p^1][0][4][row*8+j] = (short)xh;
            AZ1[p^1][1][4][row*8+j] = (short)xl;
        }
        __syncthreads();

        // --- z2: A = h1 planes (scale folded) + recurrent h2 ---
        floatx4 a2[2];
        #pragma unroll
        for (int i = 0; i < 2; ++i) a2[i] = (floatx4){z2b[i],z2b[i],z2b[i],z2b[i]};
        #pragma unroll
        for (int kk = 0; kk < 6; ++kk){
            short8 ah, al;
            if (kk < 4){ ah = *(const short8*)&AZ1[p^1][0][kk][l*8];   al = *(const short8*)&AZ1[p^1][1][kk][l*8]; }
            else       { ah = *(const short8*)&AH2[p][0][kk-4][l*8];   al = *(const short8*)&AH2[p][1][kk-4][l*8]; }
            #pragma unroll
            for (int i = 0; i < 2; ++i){
                const unsigned short* bp = PZ2 + (size_t)(i*6 + kk)*1024;
                short8 bh = *(const short8*)bp;
                short8 bl = *(const short8*)(bp + 512);
                a2[i] = MFMA(ah, bh, a2[i]);
                a2[i] = MFMA(al, bh, a2[i]);
                a2[i] = MFMA(ah, bl, a2[i]);
            }
        }
        #pragma unroll
        for (int i = 0; i < 2; ++i)
            #pragma unroll
            for (int r = 0; r < 4; ++r)
                ZSC[(q*4+r)*260 + 32*w + 16*i + l15] = a2[i][r];
        __syncthreads();

        // --- cell2 ---
        #pragma unroll
        for (int k2 = 0; k2 < 2; ++k2){
            const int u = u2k[k2];
            const float* zr = &ZSC[c2row*260];
            float ig = sigmoid_(zr[u]);
            float fg = sigmoid_(zr[64+u]);
            float gg = selu_(zr[128+u]);
            float og = sigmoid_(zr[192+u]);
            float c = fg*c2r[k2] + ig*gg; c2r[k2] = c;
            float h = og*selu_(c);
            unsigned short hh, hl; hilo(h, hh, hl);
            AH2[p^1][0][kk2[k2]][s2i[k2]] = (short)hh;
            AH2[p^1][1][kk2[k2]][s2i[k2]] = (short)hl;
        }
        p ^= 1;
    }
    __syncthreads();

    // ===================== bottleneck =====================
    // xz3 = bias3' + h2@(s2*Wk3)  (BN2 folded; 3-product)
    floatx4 xz3r[2];
    #pragma unroll
    for (int i = 0; i < 2; ++i) xz3r[i] = (floatx4){b3v[i],b3v[i],b3v[i],b3v[i]};
    #pragma unroll
    for (int kk = 0; kk < 2; ++kk){
        short8 ah = *(const short8*)&AH2[p][0][kk][l*8];
        short8 al = *(const short8*)&AH2[p][1][kk][l*8];
        #pragma unroll
        for (int i = 0; i < 2; ++i){
            const unsigned short* bp = PX3 + (size_t)(i*2 + kk)*1024;
            short8 bh = *(const short8*)bp;
            short8 bl = *(const short8*)(bp + 512);
            xz3r[i] = MFMA(ah, bh, xz3r[i]);
            xz3r[i] = MFMA(al, bh, xz3r[i]);
            xz3r[i] = MFMA(ah, bl, xz3r[i]);
        }
    }

    // ===================== decoder (3 barriers/step) =====================
    p = 0;
    for (int t = 0; t < TT; ++t){
        // dense(t-1) on wave0 (BN4 folded into Wd'); others go straight to z3
        if (w == 0 && t > 0){
            floatx4 ad = (floatx4){bdv,bdv,bdv,bdv};
            #pragma unroll
            for (int kk = 0; kk < 4; ++kk){
                short8 ah = *(const short8*)&AH4[p][0][kk][l*8];
                short8 al = *(const short8*)&AH4[p][1][kk][l*8];
                const unsigned short* bp = PDN + (size_t)kk*1024;
                short8 bh = *(const short8*)bp;
                short8 bl = *(const short8*)(bp + 512);
                ad = MFMA(ah, bh, ad);
                ad = MFMA(al, bh, ad);
                ad = MFMA(ah, bl, ad);
            }
            if (l15 < 8){
                #pragma unroll
                for (int r = 0; r < 4; ++r)
                    out[(size_t)(b0 + q*4 + r)*(TT*NF) + (size_t)(t-1)*NF + l15] = ad[r];
            }
        }
        floatx4 a3[2];
        #pragma unroll
        for (int i = 0; i < 2; ++i) a3[i] = xz3r[i];
        #pragma unroll
        for (int kk = 0; kk < 2; ++kk){
            short8 ah = *(const short8*)&AH3[p][0][kk][l*8];
            short8 al = *(const short8*)&AH3[p][1][kk][l*8];
            #pragma unroll
            for (int i = 0; i < 2; ++i){
                const unsigned short* bp = PZ3 + (size_t)(i*2 + kk)*1024;
                short8 bh = *(const short8*)bp;
                short8 bl = *(const short8*)(bp + 512);
                a3[i] = MFMA(ah, bh, a3[i]);
                a3[i] = MFMA(al, bh, a3[i]);
                a3[i] = MFMA(ah, bl, a3[i]);
            }
        }
        #pragma unroll
        for (int i = 0; i < 2; ++i)
            #pragma unroll
            for (int r = 0; r < 4; ++r)
                ZSC[(q*4+r)*260 + 32*w + 16*i + l15] = a3[i][r];
        __syncthreads();

        // --- cell3 (raw h; BN3 folded into Wk4) ---
        #pragma unroll
        for (int k2 = 0; k2 < 2; ++k2){
            const int u = u2k[k2];
            const float* zr = &ZSC[c2row*260];
            float ig = sigmoid_(zr[u]);
            float fg = sigmoid_(zr[64+u]);
            float gg = selu_(zr[128+u]);
            float og = sigmoid_(zr[192+u]);
            float c = fg*c3r[k2] + ig*gg; c3r[k2] = c;
            float h = og*selu_(c);
            unsigned short hh, hl; hilo(h, hh, hl);
            AH3[p^1][0][kk2[k2]][s2i[k2]] = (short)hh;
            AH3[p^1][1][kk2[k2]][s2i[k2]] = (short)hl;
        }
        __syncthreads();

        // --- z4 + cell4 (raw h; BN4 folded into Wd) ---
        floatx4 a4[4];
        #pragma unroll
        for (int i = 0; i < 4; ++i) a4[i] = (floatx4){z4b[i],z4b[i],z4b[i],z4b[i]};
        #pragma unroll
        for (int kk = 0; kk < 6; ++kk){
            short8 ah, al;
            if (kk < 2){ ah = *(const short8*)&AH3[p^1][0][kk][l*8];   al = *(const short8*)&AH3[p^1][1][kk][l*8]; }
            else       { ah = *(const short8*)&AH4[p][0][kk-2][l*8];   al = *(const short8*)&AH4[p][1][kk-2][l*8]; }
            #pragma unroll
            for (int i = 0; i < 4; ++i){
                const unsigned short* bp = PZ4 + (size_t)(i*48 + kk)*1024;
                short8 bh = *(const short8*)bp;
                short8 bl = *(const short8*)(bp + 512);
                a4[i] = MFMA(ah, bh, a4[i]);
                a4[i] = MFMA(al, bh, a4[i]);
                a4[i] = MFMA(ah, bl, a4[i]);
            }
        }
        #pragma unroll
        for (int r = 0; r < 4; ++r){
            float ig = sigmoid_(a4[0][r]);
            float fg = sigmoid_(a4[1][r]);
            float gg = selu_(a4[2][r]);
            float og = sigmoid_(a4[3][r]);
            float c = fg*c4r[r] + ig*gg; c4r[r] = c;
            float h = og*selu_(c);
            unsigned short hh, hl; hilo(h, hh, hl);
            const int s = sbase1 + (q*4+r)*8;
            AH4[p^1][0][kk1][s] = (short)hh;
            AH4[p^1][1][kk1][s] = (short)hl;
        }
        __syncthreads();
        p ^= 1;
    }

    // epilogue: dense for t = TT-1
    if (w == 0){
        floatx4 ad = (floatx4){bdv,bdv,bdv,bdv};
        #pragma unroll
        for (int kk = 0; kk < 4; ++kk){
            short8 ah = *(const short8*)&AH4[p][0][kk][l*8];
            short8 al = *(const short8*)&AH4[p][1][kk][l*8];
            const unsigned short* bp = PDN + (size_t)kk*1024;
            short8 bh = *(const short8*)bp;
            short8 bl = *(const short8*)(bp + 512);
            ad = MFMA(ah, bh, ad);
            ad = MFMA(al, bh, ad);
            ad = MFMA(ah, bl, ad);
        }
        if (l15 < 8){
            #pragma unroll
            for (int r = 0; r < 4; ++r)
                out[(size_t)(b0 + q*4 + r)*(TT*NF) + (size_t)(TT-1)*NF + l15] = ad[r];
        }
    }
}

extern "C" void kernel_launch(void* const* d_in, const int* in_sizes, int n_in,
                              void* d_out, int out_size, void* d_ws, size_t ws_size,
                              hipStream_t stream) {
    const float* x   = (const float*)d_in[0];
    const float* Wk1 = (const float*)d_in[1];  const float* Wr1 = (const float*)d_in[2];
    const float* b1  = (const float*)d_in[3];
    const float* g1  = (const float*)d_in[4];  const float* be1 = (const float*)d_in[5];
    const float* m1  = (const float*)d_in[6];  const float* v1  = (const float*)d_in[7];
    const float* Wk2 = (const float*)d_in[8];  const float* Wr2 = (const float*)d_in[9];
    const float* b2  = (const float*)d_in[10];
    const float* g2  = (const float*)d_in[11]; const float* be2 = (const float*)d_in[12];
    const float* m2  = (const float*)d_in[13]; const float* v2  = (const float*)d_in[14];
    const float* Wk3 = (const float*)d_in[15]; const float* Wr3 = (const float*)d_in[16];
    const float* b3  = (const float*)d_in[17];
    const float* g3  = (const float*)d_in[18]; const float* be3 = (const float*)d_in[19];
    const float* m3  = (const float*)d_in[20]; const float* v3  = (const float*)d_in[21];
    const float* Wk4 = (const float*)d_in[22]; const float* Wr4 = (const float*)d_in[23];
    const float* b4  = (const float*)d_in[24];
    const float* g4  = (const float*)d_in[25]; const float* be4 = (const float*)d_in[26];
    const float* m4  = (const float*)d_in[27]; const float* v4  = (const float*)d_in[28];
    const float* Wd  = (const float*)d_in[29]; const float* bd  = (const float*)d_in[30];

    unsigned short* ws = (unsigned short*)d_ws;

    pack_kernel<<<dim3(N_FRAGS + 4), dim3(64), 0, stream>>>(
        Wk1, Wr1, Wk2, Wr2, Wk3, Wr3, Wk4, Wr4, Wd,
        g1, be1, m1, v1, g2, be2, m2, v2,
        g3, be3, m3, v3, g4, be4, m4, v4,
        b2, b3, b4, bd, ws);
    lstm_ae_mfma<<<dim3(NBLK), dim3(NTH), 0, stream>>>(
        x, b1, (const unsigned short*)ws, (float*)d_out);
}

// Round 8
// 865.261 us; speedup vs baseline: 2.1152x; 2.1152x over previous
//
#include <hip/hip_runtime.h>
#include <math.h>

// LSTM autoencoder, MFMA, R8 = R7 skeleton + R4 numerics (the only B-hi-only
// config with measured accuracy margin: absmax 0.0068 vs threshold 0.0131).
//  - NO BN fold: raw weights in fragments; BN applied in VALU at cell time,
//    producing explicit BN'd hi/lo planes (AH1B / AH3B / AH4B).
//  - B fragments pinned in AGPRs ("a" asm constraint) - encoder 128 AGPR,
//    decoder 128 AGPR, disjoint live ranges.
//  - A (state) = RNE-hi + trunc-lo, 2 MFMA per tile-kk; one-time xz3 = 3 MFMA.
//  - decoder: waves0-3 own all 4 z3 gates (cell3 in registers), wave4 dense.
// 128 blocks x 512 threads, BT=16 rows/block.

typedef __attribute__((ext_vector_type(8))) short short8;
typedef __attribute__((ext_vector_type(4))) float floatx4;

#define TT 128
#define NF 8
#define BT 16
#define NBLK 128
#define NTH 512

// packed-fragment start indices (in 1024-ushort frag units); hi at +0, lo at +512
#define FS_Z1 0     // K'=160 (Wr1 128 | Wk1 8 | pad), N=512 : 32 tiles x 5 ks
#define FS_Z2 160   // K'=192 (Wk2 128 | Wr2 64),     N=256 : 16 x 6
#define FS_X3 256   // K =64  (Wk3),                  N=256 : 16 x 2
#define FS_Z3 288   // K =64  (Wr3),                  N=256 : 16 x 2
#define FS_Z4 320   // K'=192 (Wk4 64 | Wr4 128),     N=512 : 32 x 6
#define FS_DN 512   // K =128 (Wd), N=16 (cols 8-15 zero) : 1 x 4
#define N_FRAGS 516

#define MFMA(a,b,c) __builtin_amdgcn_mfma_f32_16x16x32_bf16((a),(b),(c),0,0,0)
#define PINA(v) asm volatile("" : "+a"(v))

__device__ __forceinline__ unsigned short bf16hi(float x){ // RNE
    unsigned u = __float_as_uint(x);
    u += 0x7fffu + ((u >> 16) & 1u);
    return (unsigned short)(u >> 16);
}
__device__ __forceinline__ unsigned short bf16tr(float x){ // truncate
    return (unsigned short)(__float_as_uint(x) >> 16);
}
__device__ __forceinline__ float bf16f(unsigned short h){
    return __uint_as_float(((unsigned)h) << 16);
}
__device__ __forceinline__ void hilo(float x, unsigned short& hi, unsigned short& lo){
    hi = bf16hi(x);
    lo = bf16tr(x - bf16f(hi));
}
__device__ __forceinline__ float sigmoid_(float x){ return 1.0f/(1.0f+__expf(-x)); }
__device__ __forceinline__ float selu_(float x){
    const float alpha = 1.6732632423543772f, scale = 1.0507009873554805f;
    return x > 0.0f ? scale*x : scale*alpha*(__expf(x)-1.0f);
}

// ---------------- pack kernel: RAW weights -> B-fragment order, bf16 hi/lo --
__global__ void pack_kernel(const float* __restrict__ Wk1, const float* __restrict__ Wr1,
                            const float* __restrict__ Wk2, const float* __restrict__ Wr2,
                            const float* __restrict__ Wk3, const float* __restrict__ Wr3,
                            const float* __restrict__ Wk4, const float* __restrict__ Wr4,
                            const float* __restrict__ Wd, unsigned short* __restrict__ ws)
{
    const int g = blockIdx.x;
    const int l = threadIdx.x;
    int blob, fs, KS;
    if      (g < FS_Z2){ blob = 0; fs = FS_Z1; KS = 5; }
    else if (g < FS_X3){ blob = 1; fs = FS_Z2; KS = 6; }
    else if (g < FS_Z3){ blob = 2; fs = FS_X3; KS = 2; }
    else if (g < FS_Z4){ blob = 3; fs = FS_Z3; KS = 2; }
    else if (g < FS_DN){ blob = 4; fs = FS_Z4; KS = 6; }
    else               { blob = 5; fs = FS_DN; KS = 4; }
    const int fl = g - fs;
    const int tile = fl / KS, kk = fl % KS;
    const int col = tile * 16 + (l & 15);
    const int k0  = kk * 32 + (l >> 4) * 8;

    short8 hi8, lo8;
    #pragma unroll
    for (int j = 0; j < 8; ++j){
        const int k = k0 + j;
        float v = 0.0f;
        switch (blob){
            case 0: v = (k < 128) ? Wr1[k*512 + col] : (k < 136 ? Wk1[(k-128)*512 + col] : 0.0f); break;
            case 1: v = (k < 128) ? Wk2[k*256 + col] : Wr2[(k-128)*256 + col]; break;
            case 2: v = Wk3[k*256 + col]; break;
            case 3: v = Wr3[k*256 + col]; break;
            case 4: v = (k < 64) ? Wk4[k*512 + col] : Wr4[(k-64)*512 + col]; break;
            case 5: v = (col < 8) ? Wd[k*8 + col] : 0.0f; break;
        }
        unsigned short h = bf16hi(v);
        unsigned short lo = bf16hi(v - bf16f(h));
        hi8[j] = (short)h; lo8[j] = (short)lo;
    }
    *(short8*)(ws + (size_t)g*1024 + l*8)       = hi8;
    *(short8*)(ws + (size_t)g*1024 + 512 + l*8) = lo8;
}

// ---------------- main kernel ------------------------------------------------
__global__ __launch_bounds__(NTH, 1) void lstm_ae_mfma(
    const float* __restrict__ x,
    const float* __restrict__ b1, const float* __restrict__ b2,
    const float* __restrict__ b3, const float* __restrict__ b4,
    const float* __restrict__ bd,
    const float* __restrict__ g1, const float* __restrict__ be1, const float* __restrict__ m1, const float* __restrict__ v1,
    const float* __restrict__ g2, const float* __restrict__ be2, const float* __restrict__ m2, const float* __restrict__ v2,
    const float* __restrict__ g3, const float* __restrict__ be3, const float* __restrict__ m3, const float* __restrict__ v3,
    const float* __restrict__ g4, const float* __restrict__ be4, const float* __restrict__ m4, const float* __restrict__ v4,
    const unsigned short* __restrict__ WS,
    float* __restrict__ out)
{
    // A-fragment planes: [hi/lo][kk][lane*8 + j]
    __shared__ __align__(16) short AZ1[2][2][5][512];   // h1 (kk 0-3) + x (kk 4)
    __shared__ __align__(16) short AH1B[2][4][512];     // BN1(h1)
    __shared__ __align__(16) short AH2[2][2][2][512];
    __shared__ __align__(16) short AH3[2][2][2][512];
    __shared__ __align__(16) short AH3B[2][2][512];     // enc planes, then BN3(h3)
    __shared__ __align__(16) short AH4[2][2][4][512];
    __shared__ __align__(16) short AH4B[2][4][512];     // BN4(h4)
    __shared__ __align__(16) float ZSC[16*260];         // encoder z2 scratch

    const int tid = threadIdx.x;
    const int w = tid >> 6, l = tid & 63;
    const int l15 = l & 15, q = l >> 4;
    const int b0 = blockIdx.x * BT;

    // ---- per-lane constants ----
    const int u1 = 16*w + l15;                   // z1/z4 cell column (0..127)
    const int kk1 = u1 >> 5;
    const int sbase1 = ((u1>>3)&3)*128 + (u1&7);
    const float s1v = g1[u1]*rsqrtf(v1[u1]+1e-3f), t1v = be1[u1]-m1[u1]*s1v;
    const float s4v = g4[u1]*rsqrtf(v4[u1]+1e-3f), t4v = be4[u1]-m4[u1]*s4v;

    // encoder cell2 mapping (ZSC scheme)
    const int c2row = l15;
    int kk2[2], s2i[2], u2k[2];
    float s2r[2], t2r[2];
    #pragma unroll
    for (int k2 = 0; k2 < 2; ++k2){
        const int u = (l>>4) + 4*w + 32*k2;
        u2k[k2] = u;
        kk2[k2] = u >> 5;
        s2i[k2] = (((u>>3)&3)*16 + c2row)*8 + (u&7);
        float s2 = g2[u]*rsqrtf(v2[u]+1e-3f); s2r[k2]=s2; t2r[k2]=be2[u]-m2[u]*s2;
    }
    // decoder cell3 mapping (waves 0-3 own all gates of column u3)
    const int u3 = 16*(w&3) + l15;               // 0..63
    const int kk3 = u3 >> 5;
    const float s3v = g3[u3 & 63]*rsqrtf(v3[u3 & 63]+1e-3f);
    const float t3v = be3[u3 & 63]-m3[u3 & 63]*s3v;

    float z1b[4], z4b[4], z2b[2];
    #pragma unroll
    for (int i = 0; i < 4; ++i){
        z1b[i] = b1[(w + 8*i)*16 + l15];
        z4b[i] = b4[(w + 8*i)*16 + l15];
    }
    #pragma unroll
    for (int i = 0; i < 2; ++i)
        z2b[i] = b2[32*w + 16*i + l15];
    float b3v[4];
    #pragma unroll
    for (int i = 0; i < 4; ++i)
        b3v[i] = (w < 4) ? b3[((w&3) + 4*i)*16 + l15] : 0.0f;
    const float bdv = (w == 4 && l15 < 8) ? bd[l15] : 0.0f;

    // ---- encoder weights (hi halves) pinned in AGPRs ----
    short8 wz1[4][5], wz2[2][6];
    #pragma unroll
    for (int i = 0; i < 4; ++i)
        #pragma unroll
        for (int kk = 0; kk < 5; ++kk){
            wz1[i][kk] = *(const short8*)(WS + (size_t)(FS_Z1 + (w+8*i)*5 + kk)*1024 + l*8);
            PINA(wz1[i][kk]);
        }
    #pragma unroll
    for (int i = 0; i < 2; ++i)
        #pragma unroll
        for (int kk = 0; kk < 6; ++kk){
            wz2[i][kk] = *(const short8*)(WS + (size_t)(FS_Z2 + (2*w+i)*6 + kk)*1024 + l*8);
            PINA(wz2[i][kk]);
        }

    // ---- prologue: zero t=0 state planes, stage x[0] ----
    for (int i = tid; i < 5120; i += NTH) ((int*)AZ1)[i] = 0;
    for (int i = tid; i < 2048; i += NTH){ ((int*)AH2)[i] = 0; ((int*)AH3)[i] = 0; }
    for (int i = tid; i < 4096; i += NTH) ((int*)AH4)[i] = 0;
    if (tid < 128){
        int row = tid >> 3, j = tid & 7;
        unsigned short xh, xl;
        hilo(x[(size_t)(b0+row)*(TT*NF) + j], xh, xl);
        AZ1[0][0][4][row*8+j] = (short)xh;
        AZ1[0][1][4][row*8+j] = (short)xl;
    }
    float c1r[4] = {0,0,0,0}, c4r[4] = {0,0,0,0};
    float c2r[2] = {0,0},     c3r[4] = {0,0,0,0};
    __syncthreads();

    // ===================== encoder (2 barriers/step) =====================
    int p = 0;
    for (int t = 0; t < TT; ++t){
        float xnext = 0.0f;
        if (tid < 128 && t+1 < TT)
            xnext = x[(size_t)(b0+(tid>>3))*(TT*NF) + (size_t)(t+1)*NF + (tid&7)];

        // --- z1: A hi/lo from LDS, B hi from AGPR ---
        floatx4 acc[4];
        #pragma unroll
        for (int i = 0; i < 4; ++i) acc[i] = (floatx4){z1b[i],z1b[i],z1b[i],z1b[i]};
        #pragma unroll
        for (int kk = 0; kk < 5; ++kk){
            short8 ah = *(const short8*)&AZ1[p][0][kk][l*8];
            short8 al = *(const short8*)&AZ1[p][1][kk][l*8];
            #pragma unroll
            for (int i = 0; i < 4; ++i){
                acc[i] = MFMA(ah, wz1[i][kk], acc[i]);
                acc[i] = MFMA(al, wz1[i][kk], acc[i]);
            }
        }
        // --- cell1: raw h (AZ1) + BN1(h) (AH1B) ---
        #pragma unroll
        for (int r = 0; r < 4; ++r){
            float ig = sigmoid_(acc[0][r]);
            float fg = sigmoid_(acc[1][r]);
            float gg = selu_(acc[2][r]);
            float og = sigmoid_(acc[3][r]);
            float c = fg*c1r[r] + ig*gg; c1r[r] = c;
            float h = og*selu_(c);
            float hb = h*s1v + t1v;
            const int s = sbase1 + (q*4+r)*8;
            unsigned short hh, hl; hilo(h, hh, hl);
            AZ1[p^1][0][kk1][s] = (short)hh;
            AZ1[p^1][1][kk1][s] = (short)hl;
            unsigned short bh_, bl_; hilo(hb, bh_, bl_);
            AH1B[0][kk1][s] = (short)bh_;
            AH1B[1][kk1][s] = (short)bl_;
        }
        if (tid < 128 && t+1 < TT){
            int row = tid >> 3, j = tid & 7;
            unsigned short xh, xl; hilo(xnext, xh, xl);
            AZ1[p^1][0][4][row*8+j] = (short)xh;
            AZ1[p^1][1][4][row*8+j] = (short)xl;
        }
        __syncthreads();

        // --- z2 -> ZSC (A: BN1 planes kk<4, recurrent h2 kk>=4) ---
        floatx4 a2[2];
        #pragma unroll
        for (int i = 0; i < 2; ++i) a2[i] = (floatx4){z2b[i],z2b[i],z2b[i],z2b[i]};
        #pragma unroll
        for (int kk = 0; kk < 6; ++kk){
            short8 ah, al;
            if (kk < 4){ ah = *(const short8*)&AH1B[0][kk][l*8];       al = *(const short8*)&AH1B[1][kk][l*8]; }
            else       { ah = *(const short8*)&AH2[p][0][kk-4][l*8];   al = *(const short8*)&AH2[p][1][kk-4][l*8]; }
            #pragma unroll
            for (int i = 0; i < 2; ++i){
                a2[i] = MFMA(ah, wz2[i][kk], a2[i]);
                a2[i] = MFMA(al, wz2[i][kk], a2[i]);
            }
        }
        #pragma unroll
        for (int i = 0; i < 2; ++i)
            #pragma unroll
            for (int r = 0; r < 4; ++r)
                ZSC[(q*4+r)*260 + 32*w + 16*i + l15] = a2[i][r];
        __syncthreads();

        // --- cell2 ---
        #pragma unroll
        for (int k2 = 0; k2 < 2; ++k2){
            const int u = u2k[k2];
            const float* zr = &ZSC[c2row*260];
            float ig = sigmoid_(zr[u]);
            float fg = sigmoid_(zr[64+u]);
            float gg = selu_(zr[128+u]);
            float og = sigmoid_(zr[192+u]);
            float c = fg*c2r[k2] + ig*gg; c2r[k2] = c;
            float h = og*selu_(c);
            unsigned short hh, hl; hilo(h, hh, hl);
            AH2[p^1][0][kk2[k2]][s2i[k2]] = (short)hh;
            AH2[p^1][1][kk2[k2]][s2i[k2]] = (short)hl;
        }
        p ^= 1;
    }
    __syncthreads();

    // ===================== bottleneck =====================
    // encb = BN2(h2_final) -> AH3B planes (hi/lo)
    #pragma unroll
    for (int k2 = 0; k2 < 2; ++k2){
        float h2v = bf16f((unsigned short)AH2[p][0][kk2[k2]][s2i[k2]])
                  + bf16f((unsigned short)AH2[p][1][kk2[k2]][s2i[k2]]);
        float e = h2v*s2r[k2] + t2r[k2];
        unsigned short eh, el; hilo(e, eh, el);
        AH3B[0][kk2[k2]][s2i[k2]] = (short)eh;
        AH3B[1][kk2[k2]][s2i[k2]] = (short)el;
    }
    __syncthreads();
    // xz3 = b3 + encb@Wk3  (one-time, 3-product streamed hi/lo raw B)
    floatx4 xz3r[4];
    if (w < 4){
        #pragma unroll
        for (int i = 0; i < 4; ++i) xz3r[i] = (floatx4){b3v[i],b3v[i],b3v[i],b3v[i]};
        #pragma unroll
        for (int kk = 0; kk < 2; ++kk){
            short8 ah = *(const short8*)&AH3B[0][kk][l*8];
            short8 al = *(const short8*)&AH3B[1][kk][l*8];
            #pragma unroll
            for (int i = 0; i < 4; ++i){
                const unsigned short* bp = WS + (size_t)(FS_X3 + ((w&3)+4*i)*2 + kk)*1024 + l*8;
                short8 bh = *(const short8*)bp;
                short8 bl = *(const short8*)(bp + 512);
                xz3r[i] = MFMA(ah, bh, xz3r[i]);
                xz3r[i] = MFMA(al, bh, xz3r[i]);
                xz3r[i] = MFMA(ah, bl, xz3r[i]);
            }
        }
    }

    // ---- decoder weights pinned in AGPRs (encoder AGPRs now dead) ----
    short8 wz4[4][6], wrole[8];
    #pragma unroll
    for (int i = 0; i < 4; ++i)
        #pragma unroll
        for (int kk = 0; kk < 6; ++kk){
            wz4[i][kk] = *(const short8*)(WS + (size_t)(FS_Z4 + (w+8*i)*6 + kk)*1024 + l*8);
            PINA(wz4[i][kk]);
        }
    if (w < 4){
        #pragma unroll
        for (int i = 0; i < 4; ++i)
            #pragma unroll
            for (int kk = 0; kk < 2; ++kk){
                wrole[i*2+kk] = *(const short8*)(WS + (size_t)(FS_Z3 + ((w&3)+4*i)*2 + kk)*1024 + l*8);
                PINA(wrole[i*2+kk]);
            }
    } else if (w == 4){
        #pragma unroll
        for (int kk = 0; kk < 4; ++kk){
            wrole[kk] = *(const short8*)(WS + (size_t)(FS_DN + kk)*1024 + l*8);
            PINA(wrole[kk]);
        }
    }
    __syncthreads();   // AH3B reuse: enc-plane reads must finish before cell3 writes

    // ===================== decoder (2 barriers/step) =====================
    p = 0;
    for (int t = 0; t < TT; ++t){
        if (w < 4){
            // --- z3 (waves0-3, all 4 gates) + cell3 in registers ---
            floatx4 a3[4];
            #pragma unroll
            for (int i = 0; i < 4; ++i) a3[i] = xz3r[i];
            #pragma unroll
            for (int kk = 0; kk < 2; ++kk){
                short8 ah = *(const short8*)&AH3[p][0][kk][l*8];
                short8 al = *(const short8*)&AH3[p][1][kk][l*8];
                #pragma unroll
                for (int i = 0; i < 4; ++i){
                    a3[i] = MFMA(ah, wrole[i*2+kk], a3[i]);
                    a3[i] = MFMA(al, wrole[i*2+kk], a3[i]);
                }
            }
            #pragma unroll
            for (int r = 0; r < 4; ++r){
                float ig = sigmoid_(a3[0][r]);
                float fg = sigmoid_(a3[1][r]);
                float gg = selu_(a3[2][r]);
                float og = sigmoid_(a3[3][r]);
                float c = fg*c3r[r] + ig*gg; c3r[r] = c;
                float h = og*selu_(c);
                float hb = h*s3v + t3v;
                const int s = (((u3>>3)&3)*16 + (q*4+r))*8 + (u3&7);
                unsigned short hh, hl; hilo(h, hh, hl);
                AH3[p^1][0][kk3][s] = (short)hh;
                AH3[p^1][1][kk3][s] = (short)hl;
                unsigned short bh_, bl_; hilo(hb, bh_, bl_);
                AH3B[0][kk3][s] = (short)bh_;
                AH3B[1][kk3][s] = (short)bl_;
            }
        } else if (w == 4 && t > 0){
            // --- dense(t-1) on wave4 (A = BN4 planes, B = raw Wd hi) ---
            floatx4 ad = (floatx4){bdv,bdv,bdv,bdv};
            #pragma unroll
            for (int kk = 0; kk < 4; ++kk){
                short8 ah = *(const short8*)&AH4B[0][kk][l*8];
                short8 al = *(const short8*)&AH4B[1][kk][l*8];
                ad = MFMA(ah, wrole[kk], ad);
                ad = MFMA(al, wrole[kk], ad);
            }
            if (l15 < 8){
                #pragma unroll
                for (int r = 0; r < 4; ++r)
                    out[(size_t)(b0 + q*4 + r)*(TT*NF) + (size_t)(t-1)*NF + l15] = ad[r];
            }
        }
        __syncthreads();

        // --- z4 + cell4 (all waves); A kk<2 = BN3 planes, kk>=2 = raw h4 ---
        floatx4 a4[4];
        #pragma unroll
        for (int i = 0; i < 4; ++i) a4[i] = (floatx4){z4b[i],z4b[i],z4b[i],z4b[i]};
        #pragma unroll
        for (int kk = 0; kk < 6; ++kk){
            short8 ah, al;
            if (kk < 2){ ah = *(const short8*)&AH3B[0][kk][l*8];       al = *(const short8*)&AH3B[1][kk][l*8]; }
            else       { ah = *(const short8*)&AH4[p][0][kk-2][l*8];   al = *(const short8*)&AH4[p][1][kk-2][l*8]; }
            #pragma unroll
            for (int i = 0; i < 4; ++i){
                a4[i] = MFMA(ah, wz4[i][kk], a4[i]);
                a4[i] = MFMA(al, wz4[i][kk], a4[i]);
            }
        }
        #pragma unroll
        for (int r = 0; r < 4; ++r){
            float ig = sigmoid_(a4[0][r]);
            float fg = sigmoid_(a4[1][r]);
            float gg = selu_(a4[2][r]);
            float og = sigmoid_(a4[3][r]);
            float c = fg*c4r[r] + ig*gg; c4r[r] = c;
            float h = og*selu_(c);
            float hb = h*s4v + t4v;
            const int s = sbase1 + (q*4+r)*8;
            unsigned short hh, hl; hilo(h, hh, hl);
            AH4[p^1][0][kk1][s] = (short)hh;
            AH4[p^1][1][kk1][s] = (short)hl;
            unsigned short bh_, bl_; hilo(hb, bh_, bl_);
            AH4B[0][kk1][s] = (short)bh_;
            AH4B[1][kk1][s] = (short)bl_;
        }
        __syncthreads();
        p ^= 1;
    }

    // epilogue: dense for t = TT-1 (wave4)
    if (w == 4){
        floatx4 ad = (floatx4){bdv,bdv,bdv,bdv};
        #pragma unroll
        for (int kk = 0; kk < 4; ++kk){
            short8 ah = *(const short8*)&AH4B[0][kk][l*8];
            short8 al = *(const short8*)&AH4B[1][kk][l*8];
            ad = MFMA(ah, wrole[kk], ad);
            ad = MFMA(al, wrole[kk], ad);
        }
        if (l15 < 8){
            #pragma unroll
            for (int r = 0; r < 4; ++r)
                out[(size_t)(b0 + q*4 + r)*(TT*NF) + (size_t)(TT-1)*NF + l15] = ad[r];
        }
    }
}

extern "C" void kernel_launch(void* const* d_in, const int* in_sizes, int n_in,
                              void* d_out, int out_size, void* d_ws, size_t ws_size,
                              hipStream_t stream) {
    const float* x   = (const float*)d_in[0];
    const float* Wk1 = (const float*)d_in[1];  const float* Wr1 = (const float*)d_in[2];
    const float* b1  = (const float*)d_in[3];
    const float* g1  = (const float*)d_in[4];  const float* be1 = (const float*)d_in[5];
    const float* m1  = (const float*)d_in[6];  const float* v1  = (const float*)d_in[7];
    const float* Wk2 = (const float*)d_in[8];  const float* Wr2 = (const float*)d_in[9];
    const float* b2  = (const float*)d_in[10];
    const float* g2  = (const float*)d_in[11]; const float* be2 = (const float*)d_in[12];
    const float* m2  = (const float*)d_in[13]; const float* v2  = (const float*)d_in[14];
    const float* Wk3 = (const float*)d_in[15]; const float* Wr3 = (const float*)d_in[16];
    const float* b3  = (const float*)d_in[17];
    const float* g3  = (const float*)d_in[18]; const float* be3 = (const float*)d_in[19];
    const float* m3  = (const float*)d_in[20]; const float* v3  = (const float*)d_in[21];
    const float* Wk4 = (const float*)d_in[22]; const float* Wr4 = (const float*)d_in[23];
    const float* b4  = (const float*)d_in[24];
    const float* g4  = (const float*)d_in[25]; const float* be4 = (const float*)d_in[26];
    const float* m4  = (const float*)d_in[27]; const float* v4  = (const float*)d_in[28];
    const float* Wd  = (const float*)d_in[29]; const float* bd  = (const float*)d_in[30];

    unsigned short* ws = (unsigned short*)d_ws;

    pack_kernel<<<dim3(N_FRAGS), dim3(64), 0, stream>>>(Wk1, Wr1, Wk2, Wr2, Wk3, Wr3,
                                                        Wk4, Wr4, Wd, ws);
    lstm_ae_mfma<<<dim3(NBLK), dim3(NTH), 0, stream>>>(
        x, b1, b2, b3, b4, bd,
        g1, be1, m1, v1, g2, be2, m2, v2,
        g3, be3, m3, v3, g4, be4, m4, v4,
        (const unsigned short*)ws, (float*)d_out);
}

// Round 9
// 737.917 us; speedup vs baseline: 2.4802x; 1.1726x over previous
//
#include <hip/hip_runtime.h>
#include <math.h>

// LSTM autoencoder, MFMA, R9 = R8 structure with fp16 single-product numerics.
// fp16 (11 mantissa bits) replaces bf16-hi/lo: one mfma_f32_16x16x32_f16 per
// tile-kk (was 2), single fp16 state planes (was hi/lo pairs), one v_cvt per
// state value (was 4-op hilo). Quantization ~2^-11 per operand, ~4x finer
// than R4's measured-passing bf16-B error (absmax 0.0068 vs thr 0.0131).
//  - NO BN fold (R5/R7 showed fold+requantization costs 2x accuracy).
//  - B fragments pinned in AGPRs; encoder/decoder sets disjoint.
//  - decoder: waves0-3 own all 4 z3 gates (cell3 in registers), wave4 dense.
// 128 blocks x 512 threads, BT=16 rows/block.

typedef _Float16 half8 __attribute__((ext_vector_type(8)));
typedef __attribute__((ext_vector_type(4))) float floatx4;

#define TT 128
#define NF 8
#define BT 16
#define NBLK 128
#define NTH 512

// packed-fragment start indices (in 512-ushort frag units, single fp16 plane)
#define FS_Z1 0     // K'=160 (Wr1 128 | Wk1 8 | pad), N=512 : 32 tiles x 5 ks
#define FS_Z2 160   // K'=192 (Wk2 128 | Wr2 64),     N=256 : 16 x 6
#define FS_X3 256   // K =64  (Wk3),                  N=256 : 16 x 2
#define FS_Z3 288   // K =64  (Wr3),                  N=256 : 16 x 2
#define FS_Z4 320   // K'=192 (Wk4 64 | Wr4 128),     N=512 : 32 x 6
#define FS_DN 512   // K =128 (Wd), N=16 (cols 8-15 zero) : 1 x 4
#define N_FRAGS 516

#define MFMAH(a,b,c) __builtin_amdgcn_mfma_f32_16x16x32_f16((a),(b),(c),0,0,0)
#define PINA(v) asm volatile("" : "+a"(v))

__device__ __forceinline__ float sigmoid_(float x){ return 1.0f/(1.0f+__expf(-x)); }
__device__ __forceinline__ float selu_(float x){
    const float alpha = 1.6732632423543772f, scale = 1.0507009873554805f;
    return x > 0.0f ? scale*x : scale*alpha*(__expf(x)-1.0f);
}

// ---------------- pack kernel: RAW weights -> B-fragment order, fp16 --------
__global__ void pack_kernel(const float* __restrict__ Wk1, const float* __restrict__ Wr1,
                            const float* __restrict__ Wk2, const float* __restrict__ Wr2,
                            const float* __restrict__ Wk3, const float* __restrict__ Wr3,
                            const float* __restrict__ Wk4, const float* __restrict__ Wr4,
                            const float* __restrict__ Wd, unsigned short* __restrict__ ws)
{
    const int g = blockIdx.x;
    const int l = threadIdx.x;
    int blob, fs, KS;
    if      (g < FS_Z2){ blob = 0; fs = FS_Z1; KS = 5; }
    else if (g < FS_X3){ blob = 1; fs = FS_Z2; KS = 6; }
    else if (g < FS_Z3){ blob = 2; fs = FS_X3; KS = 2; }
    else if (g < FS_Z4){ blob = 3; fs = FS_Z3; KS = 2; }
    else if (g < FS_DN){ blob = 4; fs = FS_Z4; KS = 6; }
    else               { blob = 5; fs = FS_DN; KS = 4; }
    const int fl = g - fs;
    const int tile = fl / KS, kk = fl % KS;
    const int col = tile * 16 + (l & 15);
    const int k0  = kk * 32 + (l >> 4) * 8;

    half8 v8;
    #pragma unroll
    for (int j = 0; j < 8; ++j){
        const int k = k0 + j;
        float v = 0.0f;
        switch (blob){
            case 0: v = (k < 128) ? Wr1[k*512 + col] : (k < 136 ? Wk1[(k-128)*512 + col] : 0.0f); break;
            case 1: v = (k < 128) ? Wk2[k*256 + col] : Wr2[(k-128)*256 + col]; break;
            case 2: v = Wk3[k*256 + col]; break;
            case 3: v = Wr3[k*256 + col]; break;
            case 4: v = (k < 64) ? Wk4[k*512 + col] : Wr4[(k-64)*512 + col]; break;
            case 5: v = (col < 8) ? Wd[k*8 + col] : 0.0f; break;
        }
        v8[j] = (_Float16)v;    // RNE
    }
    *(half8*)(ws + (size_t)g*512 + l*8) = v8;
}

// ---------------- main kernel ------------------------------------------------
__global__ __launch_bounds__(NTH, 1) void lstm_ae_mfma(
    const float* __restrict__ x,
    const float* __restrict__ b1, const float* __restrict__ b2,
    const float* __restrict__ b3, const float* __restrict__ b4,
    const float* __restrict__ bd,
    const float* __restrict__ g1, const float* __restrict__ be1, const float* __restrict__ m1, const float* __restrict__ v1,
    const float* __restrict__ g2, const float* __restrict__ be2, const float* __restrict__ m2, const float* __restrict__ v2,
    const float* __restrict__ g3, const float* __restrict__ be3, const float* __restrict__ m3, const float* __restrict__ v3,
    const float* __restrict__ g4, const float* __restrict__ be4, const float* __restrict__ m4, const float* __restrict__ v4,
    const unsigned short* __restrict__ WS,
    float* __restrict__ out)
{
    // A-fragment planes, single fp16: [kk][lane*8 + j]
    __shared__ __align__(16) _Float16 AZ1[2][5][512];   // h1 (kk 0-3) + x (kk 4)
    __shared__ __align__(16) _Float16 AH1B[4][512];     // BN1(h1)
    __shared__ __align__(16) _Float16 AH2[2][2][512];
    __shared__ __align__(16) _Float16 AH3[2][2][512];
    __shared__ __align__(16) _Float16 AH3B[2][512];     // enc planes, then BN3(h3)
    __shared__ __align__(16) _Float16 AH4[2][4][512];
    __shared__ __align__(16) _Float16 AH4B[4][512];     // BN4(h4)
    __shared__ __align__(16) float ZSC[16*260];         // encoder z2 scratch

    const int tid = threadIdx.x;
    const int w = tid >> 6, l = tid & 63;
    const int l15 = l & 15, q = l >> 4;
    const int b0 = blockIdx.x * BT;

    // ---- per-lane constants ----
    const int u1 = 16*w + l15;                   // z1/z4 cell column (0..127)
    const int kk1 = u1 >> 5;
    const int sbase1 = ((u1>>3)&3)*128 + (u1&7);
    const float s1v = g1[u1]*rsqrtf(v1[u1]+1e-3f), t1v = be1[u1]-m1[u1]*s1v;
    const float s4v = g4[u1]*rsqrtf(v4[u1]+1e-3f), t4v = be4[u1]-m4[u1]*s4v;

    // encoder cell2 mapping (ZSC scheme)
    const int c2row = l15;
    int kk2[2], s2i[2], u2k[2];
    float s2r[2], t2r[2];
    #pragma unroll
    for (int k2 = 0; k2 < 2; ++k2){
        const int u = (l>>4) + 4*w + 32*k2;
        u2k[k2] = u;
        kk2[k2] = u >> 5;
        s2i[k2] = (((u>>3)&3)*16 + c2row)*8 + (u&7);
        float s2 = g2[u]*rsqrtf(v2[u]+1e-3f); s2r[k2]=s2; t2r[k2]=be2[u]-m2[u]*s2;
    }
    // decoder cell3 mapping (waves 0-3 own all gates of column u3)
    const int u3 = 16*(w&3) + l15;               // 0..63
    const int kk3 = u3 >> 5;
    const float s3v = g3[u3 & 63]*rsqrtf(v3[u3 & 63]+1e-3f);
    const float t3v = be3[u3 & 63]-m3[u3 & 63]*s3v;

    float z1b[4], z4b[4], z2b[2];
    #pragma unroll
    for (int i = 0; i < 4; ++i){
        z1b[i] = b1[(w + 8*i)*16 + l15];
        z4b[i] = b4[(w + 8*i)*16 + l15];
    }
    #pragma unroll
    for (int i = 0; i < 2; ++i)
        z2b[i] = b2[32*w + 16*i + l15];
    float b3v[4];
    #pragma unroll
    for (int i = 0; i < 4; ++i)
        b3v[i] = (w < 4) ? b3[((w&3) + 4*i)*16 + l15] : 0.0f;
    const float bdv = (w == 4 && l15 < 8) ? bd[l15] : 0.0f;

    // ---- encoder weights pinned in AGPRs ----
    half8 wz1[4][5], wz2[2][6];
    #pragma unroll
    for (int i = 0; i < 4; ++i)
        #pragma unroll
        for (int kk = 0; kk < 5; ++kk){
            wz1[i][kk] = *(const half8*)(WS + (size_t)(FS_Z1 + (w+8*i)*5 + kk)*512 + l*8);
            PINA(wz1[i][kk]);
        }
    #pragma unroll
    for (int i = 0; i < 2; ++i)
        #pragma unroll
        for (int kk = 0; kk < 6; ++kk){
            wz2[i][kk] = *(const half8*)(WS + (size_t)(FS_Z2 + (2*w+i)*6 + kk)*512 + l*8);
            PINA(wz2[i][kk]);
        }

    // ---- prologue: zero t=0 state planes (incl. x-plane pad!), stage x[0] ---
    for (int i = tid; i < 2560; i += NTH) ((int*)AZ1)[i] = 0;
    for (int i = tid; i < 1024; i += NTH){ ((int*)AH2)[i] = 0; ((int*)AH3)[i] = 0; }
    for (int i = tid; i < 2048; i += NTH) ((int*)AH4)[i] = 0;
    if (tid < 128){
        int row = tid >> 3, j = tid & 7;
        AZ1[0][4][row*8+j] = (_Float16)x[(size_t)(b0+row)*(TT*NF) + j];
    }
    float c1r[4] = {0,0,0,0}, c4r[4] = {0,0,0,0};
    float c2r[2] = {0,0},     c3r[4] = {0,0,0,0};
    __syncthreads();

    // ===================== encoder (2 barriers/step) =====================
    int p = 0;
    for (int t = 0; t < TT; ++t){
        float xnext = 0.0f;
        if (tid < 128 && t+1 < TT)
            xnext = x[(size_t)(b0+(tid>>3))*(TT*NF) + (size_t)(t+1)*NF + (tid&7)];

        // --- z1: A fp16 from LDS, B fp16 from AGPR (1 MFMA per tile-kk) ---
        floatx4 acc[4];
        #pragma unroll
        for (int i = 0; i < 4; ++i) acc[i] = (floatx4){z1b[i],z1b[i],z1b[i],z1b[i]};
        #pragma unroll
        for (int kk = 0; kk < 5; ++kk){
            half8 a = *(const half8*)&AZ1[p][kk][l*8];
            #pragma unroll
            for (int i = 0; i < 4; ++i)
                acc[i] = MFMAH(a, wz1[i][kk], acc[i]);
        }
        // --- cell1: raw h (AZ1) + BN1(h) (AH1B) ---
        #pragma unroll
        for (int r = 0; r < 4; ++r){
            float ig = sigmoid_(acc[0][r]);
            float fg = sigmoid_(acc[1][r]);
            float gg = selu_(acc[2][r]);
            float og = sigmoid_(acc[3][r]);
            float c = fg*c1r[r] + ig*gg; c1r[r] = c;
            float h = og*selu_(c);
            const int s = sbase1 + (q*4+r)*8;
            AZ1[p^1][kk1][s] = (_Float16)h;
            AH1B[kk1][s]     = (_Float16)(h*s1v + t1v);
        }
        if (tid < 128 && t+1 < TT){
            int row = tid >> 3, j = tid & 7;
            AZ1[p^1][4][row*8+j] = (_Float16)xnext;
        }
        __syncthreads();

        // --- z2 -> ZSC (A: BN1 planes kk<4, recurrent h2 kk>=4) ---
        floatx4 a2[2];
        #pragma unroll
        for (int i = 0; i < 2; ++i) a2[i] = (floatx4){z2b[i],z2b[i],z2b[i],z2b[i]};
        #pragma unroll
        for (int kk = 0; kk < 6; ++kk){
            half8 a = (kk < 4) ? *(const half8*)&AH1B[kk][l*8]
                               : *(const half8*)&AH2[p][kk-4][l*8];
            #pragma unroll
            for (int i = 0; i < 2; ++i)
                a2[i] = MFMAH(a, wz2[i][kk], a2[i]);
        }
        #pragma unroll
        for (int i = 0; i < 2; ++i)
            #pragma unroll
            for (int r = 0; r < 4; ++r)
                ZSC[(q*4+r)*260 + 32*w + 16*i + l15] = a2[i][r];
        __syncthreads();

        // --- cell2 ---
        #pragma unroll
        for (int k2 = 0; k2 < 2; ++k2){
            const int u = u2k[k2];
            const float* zr = &ZSC[c2row*260];
            float ig = sigmoid_(zr[u]);
            float fg = sigmoid_(zr[64+u]);
            float gg = selu_(zr[128+u]);
            float og = sigmoid_(zr[192+u]);
            float c = fg*c2r[k2] + ig*gg; c2r[k2] = c;
            float h = og*selu_(c);
            AH2[p^1][kk2[k2]][s2i[k2]] = (_Float16)h;
        }
        p ^= 1;
    }
    __syncthreads();

    // ===================== bottleneck =====================
    // encb = BN2(h2_final) -> AH3B planes
    #pragma unroll
    for (int k2 = 0; k2 < 2; ++k2){
        float h2v = (float)AH2[p][kk2[k2]][s2i[k2]];
        AH3B[kk2[k2]][s2i[k2]] = (_Float16)(h2v*s2r[k2] + t2r[k2]);
    }
    __syncthreads();
    // xz3 = b3 + encb@Wk3  (one-time)
    floatx4 xz3r[4];
    if (w < 4){
        #pragma unroll
        for (int i = 0; i < 4; ++i) xz3r[i] = (floatx4){b3v[i],b3v[i],b3v[i],b3v[i]};
        #pragma unroll
        for (int kk = 0; kk < 2; ++kk){
            half8 a = *(const half8*)&AH3B[kk][l*8];
            #pragma unroll
            for (int i = 0; i < 4; ++i){
                half8 b = *(const half8*)(WS + (size_t)(FS_X3 + ((w&3)+4*i)*2 + kk)*512 + l*8);
                xz3r[i] = MFMAH(a, b, xz3r[i]);
            }
        }
    }

    // ---- decoder weights pinned in AGPRs (encoder AGPRs now dead) ----
    half8 wz4[4][6], wrole[8];
    #pragma unroll
    for (int i = 0; i < 4; ++i)
        #pragma unroll
        for (int kk = 0; kk < 6; ++kk){
            wz4[i][kk] = *(const half8*)(WS + (size_t)(FS_Z4 + (w+8*i)*6 + kk)*512 + l*8);
            PINA(wz4[i][kk]);
        }
    if (w < 4){
        #pragma unroll
        for (int i = 0; i < 4; ++i)
            #pragma unroll
            for (int kk = 0; kk < 2; ++kk){
                wrole[i*2+kk] = *(const half8*)(WS + (size_t)(FS_Z3 + ((w&3)+4*i)*2 + kk)*512 + l*8);
                PINA(wrole[i*2+kk]);
            }
    } else if (w == 4){
        #pragma unroll
        for (int kk = 0; kk < 4; ++kk){
            wrole[kk] = *(const half8*)(WS + (size_t)(FS_DN + kk)*512 + l*8);
            PINA(wrole[kk]);
        }
    }
    __syncthreads();   // AH3B reuse: enc-plane reads must finish before cell3 writes

    // ===================== decoder (2 barriers/step) =====================
    p = 0;
    for (int t = 0; t < TT; ++t){
        if (w < 4){
            // --- z3 (waves0-3, all 4 gates) + cell3 in registers ---
            floatx4 a3[4];
            #pragma unroll
            for (int i = 0; i < 4; ++i) a3[i] = xz3r[i];
            #pragma unroll
            for (int kk = 0; kk < 2; ++kk){
                half8 a = *(const half8*)&AH3[p][kk][l*8];
                #pragma unroll
                for (int i = 0; i < 4; ++i)
                    a3[i] = MFMAH(a, wrole[i*2+kk], a3[i]);
            }
            #pragma unroll
            for (int r = 0; r < 4; ++r){
                float ig = sigmoid_(a3[0][r]);
                float fg = sigmoid_(a3[1][r]);
                float gg = selu_(a3[2][r]);
                float og = sigmoid_(a3[3][r]);
                float c = fg*c3r[r] + ig*gg; c3r[r] = c;
                float h = og*selu_(c);
                const int s = (((u3>>3)&3)*16 + (q*4+r))*8 + (u3&7);
                AH3[p^1][kk3][s] = (_Float16)h;
                AH3B[kk3][s]     = (_Float16)(h*s3v + t3v);
            }
        } else if (w == 4 && t > 0){
            // --- dense(t-1) on wave4 (A = BN4 planes, B = Wd) ---
            floatx4 ad = (floatx4){bdv,bdv,bdv,bdv};
            #pragma unroll
            for (int kk = 0; kk < 4; ++kk){
                half8 a = *(const half8*)&AH4B[kk][l*8];
                ad = MFMAH(a, wrole[kk], ad);
            }
            if (l15 < 8){
                #pragma unroll
                for (int r = 0; r < 4; ++r)
                    out[(size_t)(b0 + q*4 + r)*(TT*NF) + (size_t)(t-1)*NF + l15] = ad[r];
            }
        }
        __syncthreads();

        // --- z4 + cell4 (all waves); A kk<2 = BN3 planes, kk>=2 = raw h4 ---
        floatx4 a4[4];
        #pragma unroll
        for (int i = 0; i < 4; ++i) a4[i] = (floatx4){z4b[i],z4b[i],z4b[i],z4b[i]};
        #pragma unroll
        for (int kk = 0; kk < 6; ++kk){
            half8 a = (kk < 2) ? *(const half8*)&AH3B[kk][l*8]
                               : *(const half8*)&AH4[p][kk-2][l*8];
            #pragma unroll
            for (int i = 0; i < 4; ++i)
                a4[i] = MFMAH(a, wz4[i][kk], a4[i]);
        }
        #pragma unroll
        for (int r = 0; r < 4; ++r){
            float ig = sigmoid_(a4[0][r]);
            float fg = sigmoid_(a4[1][r]);
            float gg = selu_(a4[2][r]);
            float og = sigmoid_(a4[3][r]);
            float c = fg*c4r[r] + ig*gg; c4r[r] = c;
            float h = og*selu_(c);
            const int s = sbase1 + (q*4+r)*8;
            AH4[p^1][kk1][s] = (_Float16)h;
            AH4B[kk1][s]     = (_Float16)(h*s4v + t4v);
        }
        __syncthreads();
        p ^= 1;
    }

    // epilogue: dense for t = TT-1 (wave4)
    if (w == 4){
        floatx4 ad = (floatx4){bdv,bdv,bdv,bdv};
        #pragma unroll
        for (int kk = 0; kk < 4; ++kk){
            half8 a = *(const half8*)&AH4B[kk][l*8];
            ad = MFMAH(a, wrole[kk], ad);
        }
        if (l15 < 8){
            #pragma unroll
            for (int r = 0; r < 4; ++r)
                out[(size_t)(b0 + q*4 + r)*(TT*NF) + (size_t)(TT-1)*NF + l15] = ad[r];
        }
    }
}

extern "C" void kernel_launch(void* const* d_in, const int* in_sizes, int n_in,
                              void* d_out, int out_size, void* d_ws, size_t ws_size,
                              hipStream_t stream) {
    const float* x   = (const float*)d_in[0];
    const float* Wk1 = (const float*)d_in[1];  const float* Wr1 = (const float*)d_in[2];
    const float* b1  = (const float*)d_in[3];
    const float* g1  = (const float*)d_in[4];  const float* be1 = (const float*)d_in[5];
    const float* m1  = (const float*)d_in[6];  const float* v1  = (const float*)d_in[7];
    const float* Wk2 = (const float*)d_in[8];  const float* Wr2 = (const float*)d_in[9];
    const float* b2  = (const float*)d_in[10];
    const float* g2  = (const float*)d_in[11]; const float* be2 = (const float*)d_in[12];
    const float* m2  = (const float*)d_in[13]; const float* v2  = (const float*)d_in[14];
    const float* Wk3 = (const float*)d_in[15]; const float* Wr3 = (const float*)d_in[16];
    const float* b3  = (const float*)d_in[17];
    const float* g3  = (const float*)d_in[18]; const float* be3 = (const float*)d_in[19];
    const float* m3  = (const float*)d_in[20]; const float* v3  = (const float*)d_in[21];
    const float* Wk4 = (const float*)d_in[22]; const float* Wr4 = (const float*)d_in[23];
    const float* b4  = (const float*)d_in[24];
    const float* g4  = (const float*)d_in[25]; const float* be4 = (const float*)d_in[26];
    const float* m4  = (const float*)d_in[27]; const float* v4  = (const float*)d_in[28];
    const float* Wd  = (const float*)d_in[29]; const float* bd  = (const float*)d_in[30];

    unsigned short* ws = (unsigned short*)d_ws;

    pack_kernel<<<dim3(N_FRAGS), dim3(64), 0, stream>>>(Wk1, Wr1, Wk2, Wr2, Wk3, Wr3,
                                                        Wk4, Wr4, Wd, ws);
    lstm_ae_mfma<<<dim3(NBLK), dim3(NTH), 0, stream>>>(
        x, b1, b2, b3, b4, bd,
        g1, be1, m1, v1, g2, be2, m2, v2,
        g3, be3, m3, v3, g4, be4, m4, v4,
        (const unsigned short*)ws, (float*)d_out);
}